// Round 10
// baseline (137.697 us; speedup 1.0000x reference)
//
#include <hip/hip_runtime.h>
#include <hip/hip_bf16.h>

// CompletePatchReadout: grouped GEMM (128 patches, M=32 K=1536 N=768) + bias + scatter.
// Round-10: K-SPLIT. Every prior kernel split N, so each 3072B W row was consumed by
// 2+ independent blocks -> boundary DRAM pages activated twice (measured 5.1 vs 6.7
// TB/s fill = 0.76 ~ predicted half-row efficiency). Now block (p,kh) reads a fully
// contiguous, unshared 2.36 MB W slab (nontemporal), computes partial over its K-half
// for ALL 768 cols, writes bf16 partials to d_ws; phase-2 kernel adds halves + bias
// and scatters. R8's proven LDS layout/swizzle/schedule kept verbatim (col -> 768).

constexpr int T      = 12;
constexpr int P      = 128;
constexpr int F      = 128;
constexpr int K      = T * F;        // 1536
constexpr int N      = 768;
constexpr int NPP    = 64;
constexpr int H      = 12;
constexpr int NNODES = P * NPP;      // 8192
constexpr int KH2    = 768;          // K half per block
constexpr int NSTEP2 = KH2 / 32;     // 24 K32 steps
constexpr int TPF    = T * P * F;
constexpr int PF     = P * F;
constexpr size_t HALF_ELE = (size_t)P * 32 * N;        // 3,145,728 partial elems/half
constexpr size_t WS_BYTES = 2 * HALF_ELE * 2;          // 12.58 MB bf16

typedef __attribute__((ext_vector_type(8))) short        bf16x8;
typedef __attribute__((ext_vector_type(4))) float        f32x4;
typedef __attribute__((ext_vector_type(4))) unsigned int u32x4;

__device__ inline unsigned short f2bfu(float f) {
    return __bfloat16_as_ushort(__float2bfloat16(f));
}
__device__ inline unsigned int pk2(float lo, float hi) {
    return (unsigned int)f2bfu(lo) | ((unsigned int)f2bfu(hi) << 16);
}
__device__ inline f32x4 ntload(const float* p) {
    return __builtin_nontemporal_load((const f32x4*)p);
}

// ---------------- phase 1: per-(patch, K-half) partial GEMM ----------------
__global__ __launch_bounds__(384, 1)
void pr_phase1(const float* __restrict__ x, const float* __restrict__ W,
               __hip_bfloat16* __restrict__ wsp_out)
{
    __shared__ short Xs[32 * KH2];        // 48 KB: x K-half, bf16, swizzled
    __shared__ short Ws2[2][4 * N * 8];   // 2 x 48 KB: W K32-tile [koct][col][8 bf16]
    char* xl  = (char*)&Xs[0];
    char* wlb = (char*)&Ws2[0][0];

    // XCD swizzle: both kh-halves of a patch on one XCD (shared L2 for x? none now,
    // but keeps W streams spread evenly over XCDs).
    const int bid = blockIdx.x;
    const int lgc = (bid & 7) * 32 + (bid >> 3);
    const int p   = lgc >> 1;
    const int kh  = lgc & 1;

    const int tid  = threadIdx.x;         // 0..383 (6 waves)
    const int lane = tid & 63;
    const int wv   = tid >> 6;            // wave -> 128-col slice
    const int r    = lane & 15;
    const int c    = lane >> 4;           // k-octet 0..3 within K32

    // --- W loaders: thread (c2,q) owns k-rows 8c2..8c2+7, cols 8q..8q+7 ---
    const int c2 = tid / 96;              // 0..3
    const int q  = tid - c2 * 96;         // 0..95
    const float* wg = W + (size_t)p * K * N + ((size_t)(kh * KH2 + 8 * c2)) * N + 8 * q;

    f32x4 ws[16];                         // 8 rows x 8 cols fp32 (2 dwordx4/row)

    auto issueW = [&](int s) {
        #pragma unroll
        for (int j = 0; j < 8; ++j) {
            const float* b = wg + (size_t)(s * 32 + j) * N;
            ws[2 * j]     = ntload(b);
            ws[2 * j + 1] = ntload(b + 4);
        }
    };

    auto writeW = [&](int d) {            // pack + transposed swizzled store (R8 layout)
        char* wl = wlb + d * 49152 + c2 * 12288;
        #pragma unroll
        for (int i = 0; i < 8; ++i) {
            const int hi = i >> 2, lo = i & 3;
            u32x4 wd;
            wd.x = pk2(ws[0  + hi][lo], ws[2  + hi][lo]);
            wd.y = pk2(ws[4  + hi][lo], ws[6  + hi][lo]);
            wd.z = pk2(ws[8  + hi][lo], ws[10 + hi][lo]);
            wd.w = pk2(ws[12 + hi][lo], ws[14 + hi][lo]);
            const int col = 8 * q + i;
            *(u32x4*)(wl + ((col * 16) ^ ((q & 7) << 4))) = wd;
        }
    };

    auto stageX = [&]() {                 // this block's K-half: 32 rows x 768 k
        const int row = tid / 12;         // 384 = 32 x 12
        const int sub = tid - row * 12;   // 64-elem chunk within the half
        const int kg0 = kh * KH2 + sub * 64;
        const int t   = kg0 >> 7;
        const int f0  = kg0 & 127;
        const float* xg = x + (size_t)row * TPF + (size_t)t * PF + (size_t)p * F + f0;
        char* xw = xl + row * 1536;
        const int sw = (row & 7) << 4;
        #pragma unroll
        for (int ci = 0; ci < 8; ++ci) {
            f32x4 v0 = *(const f32x4*)(xg + ci * 8);
            f32x4 v1 = *(const f32x4*)(xg + ci * 8 + 4);
            bf16x8 xv;
            xv[0] = (short)f2bfu(v0.x); xv[1] = (short)f2bfu(v0.y);
            xv[2] = (short)f2bfu(v0.z); xv[3] = (short)f2bfu(v0.w);
            xv[4] = (short)f2bfu(v1.x); xv[5] = (short)f2bfu(v1.y);
            xv[6] = (short)f2bfu(v1.z); xv[7] = (short)f2bfu(v1.w);
            const int ks2 = sub * 128 + ci * 16;       // byte col within half
            *(bf16x8*)(xw + (ks2 ^ sw)) = xv;
        }
    };

    f32x4 acc[2][8] = {};                 // [mi][ni] — 128 cols per wave

    auto compute = [&](int s, int d) {
        const char* wl = wlb + d * 49152 + c * 12288;
        bf16x8 af[2];
        #pragma unroll
        for (int mi = 0; mi < 2; ++mi) {
            const int row = mi * 16 + r;
            af[mi] = *(const bf16x8*)(xl + row * 1536 +
                                      ((s * 64 + c * 16) ^ ((row & 7) << 4)));
        }
        #pragma unroll
        for (int ni = 0; ni < 8; ++ni) {
            const int col = wv * 128 + ni * 16 + r;
            bf16x8 bf = *(const bf16x8*)(wl + ((col * 16) ^ (((col >> 3) & 7) << 4)));
            #pragma unroll
            for (int mi = 0; mi < 2; ++mi)
                acc[mi][ni] = __builtin_amdgcn_mfma_f32_16x16x32_bf16(
                    af[mi], bf, acc[mi][ni], 0, 0, 0);
        }
    };

    // R8-proven schedule: issue 1 tile ahead; loads never cross a barrier unwaited
    issueW(0);
    stageX();
    writeW(0);
    __syncthreads();
    issueW(1);

    for (int kt = 0; kt < NSTEP2; ++kt) {
        compute(kt, kt & 1);
        if (kt < NSTEP2 - 1) {
            writeW((kt + 1) & 1);
            __syncthreads();
            if (kt < NSTEP2 - 2) issueW(kt + 2);
        }
    }

    // partial store: ws[kh][p][b][col], contiguous, bf16
    __hip_bfloat16* wsp = wsp_out + ((size_t)(kh * P + p) * 32) * N;
    #pragma unroll
    for (int ni = 0; ni < 8; ++ni) {
        const int col = wv * 128 + ni * 16 + r;
        #pragma unroll
        for (int mi = 0; mi < 2; ++mi) {
            #pragma unroll
            for (int i = 0; i < 4; ++i) {
                const int b = mi * 16 + c * 4 + i;
                wsp[(size_t)b * N + col] = __float2bfloat16(acc[mi][ni][i]);
            }
        }
    }
}

// ---------------- phase 2: add halves + bias, permutation scatter ----------------
__global__ __launch_bounds__(256)
void pr_phase2(const __hip_bfloat16* __restrict__ wsp, const float* __restrict__ bias,
               const int* __restrict__ map, float* __restrict__ out)
{
    const size_t idx = (size_t)blockIdx.x * 256 + threadIdx.x;
    if (idx >= HALF_ELE) return;
    const int col = (int)(idx % N);
    const size_t rem = idx / N;
    const int b = (int)(rem & 31);
    const int p = (int)(rem >> 5);
    const float v = __bfloat162float(wsp[idx]) + __bfloat162float(wsp[idx + HALF_ELE])
                  + bias[p * N + col];
    const int nl = col / H;
    const int h  = col - nl * H;
    const int g  = map[p * NPP + nl];
    out[((size_t)b * NNODES + g) * H + h] = v;
}

// ---------------- fallback: round-8 kernel (BN=384 n-split), proven 125 us ----------
__global__ __launch_bounds__(384, 1)
void pr_fallback(const float* __restrict__ x, const float* __restrict__ W,
                 const float* __restrict__ bias, const int* __restrict__ map,
                 float* __restrict__ out)
{
    __shared__ short Xs[32 * K];
    __shared__ short Ws2[2][4 * 384 * 8];
    char* xl  = (char*)&Xs[0];
    char* wlb = (char*)&Ws2[0][0];

    const int bid = blockIdx.x;
    const int lgc = (bid & 7) * 32 + (bid >> 3);
    const int p   = lgc >> 1;
    const int n0  = (lgc & 1) * 384;

    const int tid  = threadIdx.x;
    const int lane = tid & 63;
    const int wv   = tid >> 6;
    const int r    = lane & 15;
    const int c    = lane >> 4;

    const int c2 = tid / 96;
    const int q  = tid - c2 * 96;
    const float* wg = W + (size_t)p * K * N + (size_t)(8 * c2) * N + (n0 + 4 * q);

    f32x4 ws[8];
    auto issueW = [&](int s) {
        #pragma unroll
        for (int j = 0; j < 8; ++j)
            ws[j] = *(const f32x4*)(wg + (size_t)(s * 32 + j) * N);
    };
    auto writeW = [&](int d) {
        char* wl = wlb + d * 24576 + c2 * 6144;
        #pragma unroll
        for (int i = 0; i < 4; ++i) {
            u32x4 wd;
            wd.x = pk2(ws[0][i], ws[1][i]);
            wd.y = pk2(ws[2][i], ws[3][i]);
            wd.z = pk2(ws[4][i], ws[5][i]);
            wd.w = pk2(ws[6][i], ws[7][i]);
            const int col = 4 * q + i;
            *(u32x4*)(wl + ((col * 16) ^ (((col >> 3) & 7) << 4))) = wd;
        }
    };
    auto stageX = [&]() {
        const int row = tid / 12;
        const int sub = tid - row * 12;
        const float* xg = x + (size_t)row * TPF + (size_t)sub * PF + (size_t)p * F;
        char* xw = xl + row * 3072;
        const int sw = (row & 7) << 4;
        #pragma unroll
        for (int ci = 0; ci < 16; ++ci) {
            f32x4 v0 = *(const f32x4*)(xg + ci * 8);
            f32x4 v1 = *(const f32x4*)(xg + ci * 8 + 4);
            bf16x8 xv;
            xv[0] = (short)f2bfu(v0.x); xv[1] = (short)f2bfu(v0.y);
            xv[2] = (short)f2bfu(v0.z); xv[3] = (short)f2bfu(v0.w);
            xv[4] = (short)f2bfu(v1.x); xv[5] = (short)f2bfu(v1.y);
            xv[6] = (short)f2bfu(v1.z); xv[7] = (short)f2bfu(v1.w);
            *(bf16x8*)(xw + ((sub * 256 + ci * 16) ^ sw)) = xv;
        }
    };

    f32x4 acc[2][4] = {};
    auto compute = [&](int s, int d) {
        const char* wl = wlb + d * 24576 + c * 6144;
        bf16x8 af[2];
        #pragma unroll
        for (int mi = 0; mi < 2; ++mi) {
            const int row = mi * 16 + r;
            af[mi] = *(const bf16x8*)(xl + row * 3072 +
                                      ((s * 64 + c * 16) ^ ((row & 7) << 4)));
        }
        #pragma unroll
        for (int ni = 0; ni < 4; ++ni) {
            const int col = wv * 64 + ni * 16 + r;
            bf16x8 bf = *(const bf16x8*)(wl + ((col * 16) ^ (((col >> 3) & 7) << 4)));
            #pragma unroll
            for (int mi = 0; mi < 2; ++mi)
                acc[mi][ni] = __builtin_amdgcn_mfma_f32_16x16x32_bf16(
                    af[mi], bf, acc[mi][ni], 0, 0, 0);
        }
    };

    issueW(0); stageX(); writeW(0);
    __syncthreads();
    issueW(1);
    for (int kt = 0; kt < 48; ++kt) {
        compute(kt, kt & 1);
        if (kt < 47) {
            writeW((kt + 1) & 1);
            __syncthreads();
            if (kt < 46) issueW(kt + 2);
        }
    }

    #pragma unroll
    for (int ni = 0; ni < 4; ++ni) {
        const int col = n0 + wv * 64 + ni * 16 + r;
        const int nl  = col / H;
        const int h   = col - nl * H;
        const int g   = map[p * NPP + nl];
        const float bv = bias[p * N + col];
        #pragma unroll
        for (int mi = 0; mi < 2; ++mi) {
            #pragma unroll
            for (int i = 0; i < 4; ++i) {
                const int b = mi * 16 + c * 4 + i;
                out[((size_t)b * NNODES + g) * H + h] = acc[mi][ni][i] + bv;
            }
        }
    }
}

extern "C" void kernel_launch(void* const* d_in, const int* in_sizes, int n_in,
                              void* d_out, int out_size, void* d_ws, size_t ws_size,
                              hipStream_t stream) {
    const float* x    = (const float*)d_in[0];
    const float* W    = (const float*)d_in[1];
    const float* bias = (const float*)d_in[2];
    const int*   map  = (const int*)d_in[3];
    float*       out  = (float*)d_out;

    if (ws_size >= WS_BYTES) {
        pr_phase1<<<dim3(256), dim3(384), 0, stream>>>(x, W, (__hip_bfloat16*)d_ws);
        const int g2 = (int)((HALF_ELE + 255) / 256);   // 12288
        pr_phase2<<<dim3(g2), dim3(256), 0, stream>>>((const __hip_bfloat16*)d_ws,
                                                      bias, map, out);
    } else {
        pr_fallback<<<dim3(256), dim3(384), 0, stream>>>(x, W, bias, map, out);
    }
}

// Round 11
// 122.280 us; speedup vs baseline: 1.1261x; 1.1261x over previous
//
#include <hip/hip_runtime.h>
#include <hip/hip_bf16.h>

// CompletePatchReadout: grouped GEMM (128 patches, M=32 K=1536 N=768) + bias + scatter.
// Round-11: DECISIVE read-path experiment. All prior structures (gather/dwordx4/zero-LDS/
// contiguous-K-split/NT/occupancy/pipelining) pinned at 4.9-5.2 TB/s read vs 6.7 fill-write.
// Only untested path: global_load_lds DMA (no VGPR return, no writeW VALU). W goes
// fp32 directly into LINEAR LDS tiles; B-fragments gathered via ds_read_b32 + hw cvt.
// If this also lands ~125 us -> machine read ceiling, declare roofline next round.

constexpr int T      = 12;
constexpr int P      = 128;
constexpr int F      = 128;
constexpr int K      = T * F;        // 1536
constexpr int N      = 768;
constexpr int NPP    = 64;
constexpr int H      = 12;
constexpr int NNODES = P * NPP;      // 8192
constexpr int BN     = 384;          // N-half per block
constexpr int NSTEP  = 48;           // K32 steps
constexpr int TPF    = T * P * F;
constexpr int PF     = P * F;

typedef __attribute__((ext_vector_type(8))) short  bf16x8;
typedef __attribute__((ext_vector_type(4))) float  f32x4;

typedef __attribute__((address_space(1))) const void  gvoid_t;
typedef __attribute__((address_space(3))) void        lvoid_t;

__device__ inline unsigned short f2bfu(float f) {
    return __bfloat16_as_ushort(__float2bfloat16(f));
}

__global__ __launch_bounds__(384, 1)
void patch_readout_kernel(const float* __restrict__ x,
                          const float* __restrict__ W,
                          const float* __restrict__ bias,
                          const int*   __restrict__ map,
                          float*       __restrict__ out)
{
    __shared__ short Xs[32 * 768];        // 48 KB: x K-half bf16, swizzled (R10-proven)
    __shared__ float Wl[2][32 * BN];      // 2 x 48 KB: W K32-tile fp32, LINEAR [k][col]
    char* xl = (char*)&Xs[0];

    // XCD swizzle (R8): 256 blocks = 8 XCDs x 32.
    const int bid = blockIdx.x;
    const int lgc = (bid & 7) * 32 + (bid >> 3);
    const int p   = lgc >> 1;
    const int n0  = (lgc & 1) * BN;

    const int tid  = threadIdx.x;         // 0..383 (6 waves)
    const int lane = tid & 63;
    const int wv   = tid >> 6;            // wave -> 64-col slice
    const int r    = lane & 15;
    const int c    = lane >> 4;           // k-octet 0..3 within K32

    // ---- W DMA source addresses: flat tile byte (wv*8192 + i*1024 + lane*16)
    //      maps to (k = flat/1536, rb = flat%1536); global = base + k*3072 + rb.
    const char* WpB = (const char*)(W + (size_t)p * K * N + n0);
    const char* wsrc[8];
    #pragma unroll
    for (int i = 0; i < 8; ++i) {
        const int flat = wv * 8192 + i * 1024 + lane * 16;
        const int k    = flat / 1536;
        const int rb   = flat - k * 1536;
        wsrc[i] = WpB + (size_t)k * 3072 + rb;
    }

    auto issueW = [&](int kt, int d) {    // 8 x 1KB DMA per wave -> 48 KB/block
        char* ldsb = (char*)&Wl[d][0] + wv * 8192;
        const size_t go = (size_t)kt * 98304;   // 32 rows x 3072 B
        #pragma unroll
        for (int i = 0; i < 8; ++i)
            __builtin_amdgcn_global_load_lds((gvoid_t*)(wsrc[i] + go),
                                             (lvoid_t*)(ldsb + i * 1024), 16, 0, 0);
    };

    auto stageX = [&](int half) {         // R10-proven: 32 rows x 768 k -> bf16 LDS
        const int row = tid / 12;
        const int sub = tid - row * 12;
        const int kg0 = half * 768 + sub * 64;
        const int t   = kg0 >> 7;
        const int f0  = kg0 & 127;
        const float* xg = x + (size_t)row * TPF + (size_t)t * PF + (size_t)p * F + f0;
        char* xw = xl + row * 1536;
        const int sw = (row & 7) << 4;
        #pragma unroll
        for (int ci = 0; ci < 8; ++ci) {
            f32x4 v0 = *(const f32x4*)(xg + ci * 8);
            f32x4 v1 = *(const f32x4*)(xg + ci * 8 + 4);
            bf16x8 xv;
            xv[0] = (short)f2bfu(v0.x); xv[1] = (short)f2bfu(v0.y);
            xv[2] = (short)f2bfu(v0.z); xv[3] = (short)f2bfu(v0.w);
            xv[4] = (short)f2bfu(v1.x); xv[5] = (short)f2bfu(v1.y);
            xv[6] = (short)f2bfu(v1.z); xv[7] = (short)f2bfu(v1.w);
            *(bf16x8*)(xw + ((sub * 128 + ci * 16) ^ sw)) = xv;
        }
    };

    f32x4 acc[2][4] = {};                 // [mi][ni]

    auto compute = [&](int sl, int d) {   // sl = local K32 step within x half
        bf16x8 af[2];
        #pragma unroll
        for (int mi = 0; mi < 2; ++mi) {
            const int row = mi * 16 + r;
            af[mi] = *(const bf16x8*)(xl + row * 1536 +
                                      ((sl * 64 + c * 16) ^ ((row & 7) << 4)));
        }
        const float* wt = &Wl[d][0];
        #pragma unroll
        for (int ni = 0; ni < 4; ++ni) {
            const int col = wv * 64 + ni * 16 + r;
            const float* wc = wt + (8 * c) * BN + col;
            bf16x8 bfv;
            #pragma unroll
            for (int j = 0; j < 8; ++j)
                bfv[j] = (short)f2bfu(wc[j * BN]);
            #pragma unroll
            for (int mi = 0; mi < 2; ++mi)
                acc[mi][ni] = __builtin_amdgcn_mfma_f32_16x16x32_bf16(
                    af[mi], bfv, acc[mi][ni], 0, 0, 0);
        }
    };

    // R8-proven schedule: 1 tile ahead; __syncthreads drains vmcnt (step >> latency)
    issueW(0, 0);
    stageX(0);
    __syncthreads();                      // tile 0 DMA + x half-0 visible
    issueW(1, 1);

    for (int kt = 0; kt < NSTEP; ++kt) {
        if (kt == 24) {                   // x half-1 restage (all waves past compute(23))
            stageX(1);
            __syncthreads();
        }
        compute(kt >= 24 ? kt - 24 : kt, kt & 1);
        if (kt < NSTEP - 1) {
            __syncthreads();              // drains tile kt+1 DMA; frees buf kt&1
            if (kt < NSTEP - 2) issueW(kt + 2, kt & 1);
        }
    }

    // ---- epilogue: bias + permutation scatter (verified layout) ----
    #pragma unroll
    for (int ni = 0; ni < 4; ++ni) {
        const int col = n0 + wv * 64 + ni * 16 + r;
        const int nl  = col / H;
        const int h   = col - nl * H;
        const int g   = map[p * NPP + nl];
        const float bv = bias[p * N + col];
        #pragma unroll
        for (int mi = 0; mi < 2; ++mi) {
            #pragma unroll
            for (int i = 0; i < 4; ++i) {
                const int b = mi * 16 + c * 4 + i;
                out[((size_t)b * NNODES + g) * H + h] = acc[mi][ni][i] + bv;
            }
        }
    }
}

extern "C" void kernel_launch(void* const* d_in, const int* in_sizes, int n_in,
                              void* d_out, int out_size, void* d_ws, size_t ws_size,
                              hipStream_t stream) {
    const float* x    = (const float*)d_in[0];
    const float* W    = (const float*)d_in[1];
    const float* bias = (const float*)d_in[2];
    const int*   map  = (const int*)d_in[3];
    float*       out  = (float*)d_out;

    dim3 grid(256);     // 1 block per CU
    dim3 block(384);
    patch_readout_kernel<<<grid, block, 0, stream>>>(x, W, bias, map, out);
}